// Round 22
// baseline (43.260 us; speedup 1.0000x reference)
//
#include <hip/hip_runtime.h>

// Constrained sparsemax: p = clip(z - tau, 0, u), tau s.t. sum p = 1.
// R22: TWO-PHASE SPLIT of R21 (best measured 28.2us).
//  Kernel A (solve, latency-bound): one wave per row. R21's fused init +
//    8 absolute probes (one interleaved DPP chain), f64 segment-Newton from
//    the margin-expanded probe bracket. Writes tau (f64) to d_ws, tau (f32)
//    and val to out. NO bulk stores -> no 66MB drain on its critical path.
//  Kernel B (emit, bandwidth-bound): pure elementwise, 256 thr/row, one
//    float4/thread: p = med3(z-tau,0,u), regions via f64 compares against
//    the SAME f64 tau, NT stores. No reductions, tiny VGPR, max TLP.

typedef float vfloat4 __attribute__((ext_vector_type(4)));

template<int CTRL>
__device__ __forceinline__ float dpp_zero(float v) {   // invalid lanes -> 0
  return __builtin_bit_cast(float,
    __builtin_amdgcn_update_dpp(0, __builtin_bit_cast(int, v), CTRL, 0xf, 0xf, true));
}
template<int CTRL>
__device__ __forceinline__ float dpp_ident(float v, float ident) { // invalid -> ident
  return __builtin_bit_cast(float,
    __builtin_amdgcn_update_dpp(__builtin_bit_cast(int, ident),
                                __builtin_bit_cast(int, v), CTRL, 0xf, 0xf, false));
}
__device__ __forceinline__ float rl63(float v) {
  return __builtin_bit_cast(float,
    __builtin_amdgcn_readlane(__builtin_bit_cast(int, v), 63));
}

__device__ __forceinline__ float wave_sum(float v) {
  v += dpp_zero<0x111>(v); v += dpp_zero<0x112>(v); v += dpp_zero<0x114>(v);
  v += dpp_zero<0x118>(v); v += dpp_zero<0x142>(v); v += dpp_zero<0x143>(v);
  return rl63(v);
}
// Fused init+probe reduction: 2 maxes + 8 sums, interleaved per level.
__device__ __forceinline__ void wave_red10(float& a, float& b,
                                           float& s1, float& s2, float& s3,
                                           float& s4, float& s5, float& s6,
                                           float& s7, float& s8) {
  const float NI = -3.4028235e38f;
#define RED10_STEP(CT) \
  a = fmaxf(a, dpp_ident<CT>(a, NI)); b = fmaxf(b, dpp_ident<CT>(b, NI)); \
  s1 += dpp_zero<CT>(s1); s2 += dpp_zero<CT>(s2); s3 += dpp_zero<CT>(s3); \
  s4 += dpp_zero<CT>(s4); s5 += dpp_zero<CT>(s5); s6 += dpp_zero<CT>(s6); \
  s7 += dpp_zero<CT>(s7); s8 += dpp_zero<CT>(s8);
  RED10_STEP(0x111) RED10_STEP(0x112) RED10_STEP(0x114)
  RED10_STEP(0x118) RED10_STEP(0x142) RED10_STEP(0x143)
#undef RED10_STEP
  a = rl63(a); b = rl63(b);
  s1 = rl63(s1); s2 = rl63(s2); s3 = rl63(s3); s4 = rl63(s4);
  s5 = rl63(s5); s6 = rl63(s6); s7 = rl63(s7); s8 = rl63(s8);
}
// solve loop: one f64 sum + one f32 sum, interleaved
__device__ __forceinline__ void wave_sumd_f(double& A, float& c) {
#define SUMD_STEP(CT) { \
  unsigned long long xa = __builtin_bit_cast(unsigned long long, A); \
  int al = __builtin_amdgcn_update_dpp(0, (int)(unsigned)xa, CT, 0xf, 0xf, true); \
  int ah = __builtin_amdgcn_update_dpp(0, (int)(xa >> 32),   CT, 0xf, 0xf, true); \
  c += dpp_zero<CT>(c); \
  A += __builtin_bit_cast(double, ((unsigned long long)(unsigned)ah << 32) | (unsigned)al); }
  SUMD_STEP(0x111) SUMD_STEP(0x112) SUMD_STEP(0x114)
  SUMD_STEP(0x118) SUMD_STEP(0x142) SUMD_STEP(0x143)
#undef SUMD_STEP
  { unsigned long long x = __builtin_bit_cast(unsigned long long, A);
    int l = __builtin_amdgcn_readlane((int)(unsigned)x, 63);
    int h = __builtin_amdgcn_readlane((int)(x >> 32), 63);
    A = __builtin_bit_cast(double, ((unsigned long long)(unsigned)h << 32) | (unsigned)l); }
  c = rl63(c);
}

// ---------------- Kernel A: solve tau per row ----------------
__global__ __launch_bounds__(64)
void csparsemax_solve(const float* __restrict__ z, const float* __restrict__ u,
                      float* __restrict__ out, double* __restrict__ tau_ws, int B) {
  constexpr int K = 1024;
  const int lane = threadIdx.x & 63;
  const int row = blockIdx.x;
  if (row >= B) return;
  const size_t base = (size_t)row * (size_t)K;

  float zf[16], uf[16];
  const vfloat4* z4p = (const vfloat4*)(z + base);
  const vfloat4* u4p = (const vfloat4*)(u + base);
  #pragma unroll
  for (int j = 0; j < 4; ++j) {
    vfloat4 a = z4p[j * 64 + lane];
    vfloat4 b = u4p[j * 64 + lane];
    zf[j*4+0] = a.x; zf[j*4+1] = a.y; zf[j*4+2] = a.z; zf[j*4+3] = a.w;
    uf[j*4+0] = b.x; uf[j*4+1] = b.y; uf[j*4+2] = b.z; uf[j*4+3] = b.w;
  }

  // fused init + 8 absolute probes (one pass, one DPP chain)
  const float P1 = 3.30f, P2 = 3.05f, P3 = 2.88f, P4 = 2.74f,
              P5 = 2.62f, P6 = 2.50f, P7 = 2.35f, P8 = 2.10f;
  float a = -3.4028235e38f, m = -3.4028235e38f;
  float A1 = 0.f, A2 = 0.f, A3 = 0.f, A4 = 0.f;
  float A5 = 0.f, A6 = 0.f, A7 = 0.f, A8 = 0.f;
  #pragma unroll
  for (int t = 0; t < 16; ++t) {
    a = fmaxf(a, uf[t] - zf[t]);
    m = fmaxf(m, zf[t]);
    A1 += fminf(fmaxf(zf[t] - P1, 0.f), uf[t]);
    A2 += fminf(fmaxf(zf[t] - P2, 0.f), uf[t]);
    A3 += fminf(fmaxf(zf[t] - P3, 0.f), uf[t]);
    A4 += fminf(fmaxf(zf[t] - P4, 0.f), uf[t]);
    A5 += fminf(fmaxf(zf[t] - P5, 0.f), uf[t]);
    A6 += fminf(fmaxf(zf[t] - P6, 0.f), uf[t]);
    A7 += fminf(fmaxf(zf[t] - P7, 0.f), uf[t]);
    A8 += fminf(fmaxf(zf[t] - P8, 0.f), uf[t]);
  }
  wave_red10(a, m, A1, A2, A3, A4, A5, A6, A7, A8);
  const float lo0 = -a, hi0 = m;
  const double glo = (double)lo0, ghi = (double)hi0;
  float lo = lo0, hi = hi0;
  float gl = 1.0e30f, gh = -1.f;
  {
    const float g1 = A1 - 1.f, g2 = A2 - 1.f, g3 = A3 - 1.f, g4 = A4 - 1.f;
    const float g5 = A5 - 1.f, g6 = A6 - 1.f, g7 = A7 - 1.f, g8 = A8 - 1.f;
    if (g1 >= 0.f)      { if (P1 > lo) { lo = P1; gl = g1; } }
    else if (g2 >= 0.f) { if (P2 > lo) { lo = P2; gl = g2; }
                          if (P1 < hi) { hi = P1; gh = g1; } }
    else if (g3 >= 0.f) { if (P3 > lo) { lo = P3; gl = g3; }
                          if (P2 < hi) { hi = P2; gh = g2; } }
    else if (g4 >= 0.f) { if (P4 > lo) { lo = P4; gl = g4; }
                          if (P3 < hi) { hi = P3; gh = g3; } }
    else if (g5 >= 0.f) { if (P5 > lo) { lo = P5; gl = g5; }
                          if (P4 < hi) { hi = P4; gh = g4; } }
    else if (g6 >= 0.f) { if (P6 > lo) { lo = P6; gl = g6; }
                          if (P5 < hi) { hi = P5; gh = g5; } }
    else if (g7 >= 0.f) { if (P7 > lo) { lo = P7; gl = g7; }
                          if (P6 < hi) { hi = P6; gh = g6; } }
    else if (g8 >= 0.f) { if (P8 > lo) { lo = P8; gl = g8; }
                          if (P7 < hi) { hi = P7; gh = g7; } }
    else                { if (P8 < hi) { hi = P8; gh = g8; } }
  }

  // f64 segment-Newton from margin-expanded probe bracket
  double dlo = fmax(glo, (double)lo - 0.01);
  double dhi = fmin(ghi, (double)hi + 0.01);
  double taud;
  {
    float seed;
    if (gl < 1.0e29f) {
      seed = (lo * gh - hi * gl) / (gh - gl);
      if (!(seed > lo && seed < hi)) seed = 0.5f * (lo + hi);
    } else {
      seed = 0.5f * (lo + hi);
    }
    taud = (double)seed;
  }
  for (int it = 0; it < 32; ++it) {
    double Fd = 0.0;
    float Cf = 0.f;
    const float tauf = (float)taud;
    #pragma unroll
    for (int t = 0; t < 16; ++t) {
      double x = (double)zf[t] - taud;
      Fd += fmin(fmax(x, 0.0), (double)uf[t]);
      float xf = zf[t] - tauf;
      Cf += (xf > 0.f && xf < uf[t]) ? 1.f : 0.f;
    }
    wave_sumd_f(Fd, Cf);
    double f = Fd;
    if (f == 1.0) break;
    if (f > 1.0) dlo = taud; else dhi = taud;
    double next;
    if (Cf > 0.5f) {
      double cand = taud + (f - 1.0) / (double)Cf;
      if (cand == taud) break;
      next = (cand > dlo && cand < dhi) ? cand : 0.5 * (dlo + dhi);
    } else {
      next = 0.5 * (dlo + dhi);
    }
    if (next == taud) break;
    taud = next;
  }

  // val (f32, R21 epilogue math) + tiny outputs
  const float tf = (float)taud;
  float vloc = 0.f;
  #pragma unroll
  for (int t = 0; t < 16; ++t) {
    float pf = fminf(fmaxf(zf[t] - tf, 0.f), uf[t]);
    float d = pf - zf[t];
    vloc = fmaf(d, d, vloc);
  }
  float vtot = wave_sum(vloc);
  if (lane == 0) {
    float* out_t = out + 2ull * (size_t)B * (size_t)K;
    float* out_v = out_t + B;
    out_t[row] = tf;
    out_v[row] = 0.5f * vtot;
    tau_ws[row] = taud;
  }
}

// ---------------- Kernel B: emit p / regions ----------------
__global__ __launch_bounds__(256)
void csparsemax_emit(const float* __restrict__ z, const float* __restrict__ u,
                     const double* __restrict__ tau_ws, float* __restrict__ out,
                     int B) {
  constexpr int K = 1024;
  const int row = blockIdx.x;
  const int tid = threadIdx.x;
  const size_t base = (size_t)row * (size_t)K;
  const double taud = tau_ws[row];
  const float tf = (float)taud;

  vfloat4 z4 = ((const vfloat4*)(z + base))[tid];
  vfloat4 u4 = ((const vfloat4*)(u + base))[tid];
  vfloat4 p4, r4;
  #pragma unroll
  for (int q = 0; q < 4; ++q) {
    float pf = fminf(fmaxf(z4[q] - tf, 0.f), u4[q]);     // v_med3_f32
    double xd = (double)z4[q] - taud;                    // numpy-exact bounds
    r4[q] = (xd <= 0.0) ? 0.f : ((xd >= (double)u4[q]) ? 2.f : 1.f);
    p4[q] = pf;
  }
  float* out_p = out;
  float* out_r = out + (size_t)B * (size_t)K;
  __builtin_nontemporal_store(p4, &((vfloat4*)(out_p + base))[tid]);
  __builtin_nontemporal_store(r4, &((vfloat4*)(out_r + base))[tid]);
}

extern "C" void kernel_launch(void* const* d_in, const int* in_sizes, int n_in,
                              void* d_out, int out_size, void* d_ws, size_t ws_size,
                              hipStream_t stream) {
  const float* z = (const float*)d_in[0];
  const float* u = (const float*)d_in[1];
  float* out = (float*)d_out;
  double* tau_ws = (double*)d_ws;
  const int K = 1024;
  const int B = in_sizes[0] / K;
  csparsemax_solve<<<B, 64, 0, stream>>>(z, u, out, tau_ws, B);
  csparsemax_emit<<<B, 256, 0, stream>>>(z, u, tau_ws, out, B);
}

// Round 23
// 28.092 us; speedup vs baseline: 1.5399x; 1.5399x over previous
//
#include <hip/hip_runtime.h>

// Constrained sparsemax: p = clip(z - tau, 0, u), tau s.t. sum p = 1.
// R21 base (best measured 28.2us): 8192 one-wave blocks, fused init+probe
// pass with one interleaved DPP chain, f64 segment-Newton (direct-clamp f64
// eval + f32 count) from the margin-expanded probe bracket, f32 epilogue
// with f64 region compares, NT stores. R22's two-kernel split regressed
// (dispatch serialization + z/u re-read) and is reverted.
// R23 change (last eval-count shave): TWELVE absolute probes
// {3.20,3.00,2.88,2.79,2.72,2.65,2.58,2.50,2.41,2.30,2.15,1.95} -- still
// one classify pass + one interleaved (2 max + 12 sum) DPP chain. Center
// windows ~0.07 (~8 breakpoints) -> ~1 fewer f64 eval typical.

typedef float vfloat4 __attribute__((ext_vector_type(4)));

template<int CTRL>
__device__ __forceinline__ float dpp_zero(float v) {   // invalid lanes -> 0
  return __builtin_bit_cast(float,
    __builtin_amdgcn_update_dpp(0, __builtin_bit_cast(int, v), CTRL, 0xf, 0xf, true));
}
template<int CTRL>
__device__ __forceinline__ float dpp_ident(float v, float ident) { // invalid -> ident
  return __builtin_bit_cast(float,
    __builtin_amdgcn_update_dpp(__builtin_bit_cast(int, ident),
                                __builtin_bit_cast(int, v), CTRL, 0xf, 0xf, false));
}
__device__ __forceinline__ float rl63(float v) {
  return __builtin_bit_cast(float,
    __builtin_amdgcn_readlane(__builtin_bit_cast(int, v), 63));
}

__device__ __forceinline__ float wave_sum(float v) {
  v += dpp_zero<0x111>(v); v += dpp_zero<0x112>(v); v += dpp_zero<0x114>(v);
  v += dpp_zero<0x118>(v); v += dpp_zero<0x142>(v); v += dpp_zero<0x143>(v);
  return rl63(v);
}
// Fused init+probe reduction: 2 maxes + 12 sums, interleaved per level ->
// one serial chain latency for all fourteen wave-uniform results.
__device__ __forceinline__ void wave_red14(float& a, float& b, float* s) {
  const float NI = -3.4028235e38f;
#define RED14_STEP(CT) \
  a = fmaxf(a, dpp_ident<CT>(a, NI)); b = fmaxf(b, dpp_ident<CT>(b, NI)); \
  s[0] += dpp_zero<CT>(s[0]);  s[1] += dpp_zero<CT>(s[1]); \
  s[2] += dpp_zero<CT>(s[2]);  s[3] += dpp_zero<CT>(s[3]); \
  s[4] += dpp_zero<CT>(s[4]);  s[5] += dpp_zero<CT>(s[5]); \
  s[6] += dpp_zero<CT>(s[6]);  s[7] += dpp_zero<CT>(s[7]); \
  s[8] += dpp_zero<CT>(s[8]);  s[9] += dpp_zero<CT>(s[9]); \
  s[10] += dpp_zero<CT>(s[10]); s[11] += dpp_zero<CT>(s[11]);
  RED14_STEP(0x111) RED14_STEP(0x112) RED14_STEP(0x114)
  RED14_STEP(0x118) RED14_STEP(0x142) RED14_STEP(0x143)
#undef RED14_STEP
  a = rl63(a); b = rl63(b);
  #pragma unroll
  for (int i = 0; i < 12; ++i) s[i] = rl63(s[i]);
}
// solve loop: one f64 sum + one f32 sum, interleaved
__device__ __forceinline__ void wave_sumd_f(double& A, float& c) {
#define SUMD_STEP(CT) { \
  unsigned long long xa = __builtin_bit_cast(unsigned long long, A); \
  int al = __builtin_amdgcn_update_dpp(0, (int)(unsigned)xa, CT, 0xf, 0xf, true); \
  int ah = __builtin_amdgcn_update_dpp(0, (int)(xa >> 32),   CT, 0xf, 0xf, true); \
  c += dpp_zero<CT>(c); \
  A += __builtin_bit_cast(double, ((unsigned long long)(unsigned)ah << 32) | (unsigned)al); }
  SUMD_STEP(0x111) SUMD_STEP(0x112) SUMD_STEP(0x114)
  SUMD_STEP(0x118) SUMD_STEP(0x142) SUMD_STEP(0x143)
#undef SUMD_STEP
  { unsigned long long x = __builtin_bit_cast(unsigned long long, A);
    int l = __builtin_amdgcn_readlane((int)(unsigned)x, 63);
    int h = __builtin_amdgcn_readlane((int)(x >> 32), 63);
    A = __builtin_bit_cast(double, ((unsigned long long)(unsigned)h << 32) | (unsigned)l); }
  c = rl63(c);
}

__global__ __launch_bounds__(64)
void csparsemax_kernel(const float* __restrict__ z, const float* __restrict__ u,
                       float* __restrict__ out, int B) {
  constexpr int K = 1024;
  const int lane = threadIdx.x & 63;
  const int row = blockIdx.x;
  if (row >= B) return;
  const size_t base = (size_t)row * (size_t)K;

  // --- load 16 elems/lane as 4x float4, coalesced ---
  float zf[16], uf[16];
  const vfloat4* z4p = (const vfloat4*)(z + base);
  const vfloat4* u4p = (const vfloat4*)(u + base);
  #pragma unroll
  for (int j = 0; j < 4; ++j) {
    vfloat4 a = z4p[j * 64 + lane];
    vfloat4 b = u4p[j * 64 + lane];
    zf[j*4+0] = a.x; zf[j*4+1] = a.y; zf[j*4+2] = a.z; zf[j*4+3] = a.w;
    uf[j*4+0] = b.x; uf[j*4+1] = b.y; uf[j*4+2] = b.z; uf[j*4+3] = b.w;
  }

  // --- fused init + 12 absolute probes (one pass, one DPP chain) ---
  const float P[12] = {3.20f, 3.00f, 2.88f, 2.79f, 2.72f, 2.65f,
                       2.58f, 2.50f, 2.41f, 2.30f, 2.15f, 1.95f};
  float a = -3.4028235e38f, m = -3.4028235e38f;
  float A[12] = {0.f,0.f,0.f,0.f,0.f,0.f,0.f,0.f,0.f,0.f,0.f,0.f};
  #pragma unroll
  for (int t = 0; t < 16; ++t) {
    a = fmaxf(a, uf[t] - zf[t]);    // lo = -max(u-z) = min(z-u)
    m = fmaxf(m, zf[t]);
    #pragma unroll
    for (int i = 0; i < 12; ++i)
      A[i] += fminf(fmaxf(zf[t] - P[i], 0.f), uf[t]);   // v_med3_f32
  }
  wave_red14(a, m, A);
  const float lo0 = -a, hi0 = m;
  const double glo = (double)lo0, ghi = (double)hi0;
  float lo = lo0, hi = hi0;
  float gl = 1.0e30f, gh = -1.f;
  {
    // g non-increasing in tau; P[0] > P[1] > ... > P[11]. Find the first
    // probe with g >= 0 scanning from the top; narrow only on true sign
    // flips; guards keep the bracket valid if a probe lies outside [lo,hi].
    int k = 12;                       // index of first probe with g>=0
    #pragma unroll
    for (int i = 11; i >= 0; --i)
      if (A[i] - 1.f >= 0.f) k = i;
    if (k < 12) {                     // P[k] is a valid lower bound
      if (P[k] > lo) { lo = P[k]; gl = A[k] - 1.f; }
      if (k > 0 && P[k-1] < hi) { hi = P[k-1]; gh = A[k-1] - 1.f; }
    } else {                          // all probes negative: root < P[11]
      if (P[11] < hi) { hi = P[11]; gh = A[11] - 1.f; }
    }
  }

  // --- f64 segment-Newton from the margin-expanded probe bracket.
  //     Margin 0.01 >= 50x the max f32 probe-sign displacement. ---
  double dlo = fmax(glo, (double)lo - 0.01);
  double dhi = fmin(ghi, (double)hi + 0.01);
  double taud;
  {
    float seed;
    if (gl < 1.0e29f) {
      seed = (lo * gh - hi * gl) / (gh - gl);      // false-position seed
      if (!(seed > lo && seed < hi)) seed = 0.5f * (lo + hi);
    } else {
      seed = 0.5f * (lo + hi);
    }
    taud = (double)seed;
  }
  for (int it = 0; it < 32; ++it) {
    // f(tau) in f64 via direct clamp (4 f64 ops/elem); count C in f32
    // (only steers the candidate -- sign of f-1 is f64-exact).
    double Fd = 0.0;
    float Cf = 0.f;
    const float tauf = (float)taud;
    #pragma unroll
    for (int t = 0; t < 16; ++t) {
      double x = (double)zf[t] - taud;
      Fd += fmin(fmax(x, 0.0), (double)uf[t]);
      float xf = zf[t] - tauf;
      Cf += (xf > 0.f && xf < uf[t]) ? 1.f : 0.f;
    }
    wave_sumd_f(Fd, Cf);
    double f = Fd;
    if (f == 1.0) break;                         // exact root
    if (f > 1.0) dlo = taud; else dhi = taud;
    double next;
    if (Cf > 0.5f) {
      double cand = taud + (f - 1.0) / (double)Cf;   // segment root
      if (cand == taud) break;                       // f64 fixed point
      next = (cand > dlo && cand < dhi) ? cand : 0.5 * (dlo + dhi);
    } else {
      next = 0.5 * (dlo + dhi);
    }
    if (next == taud) break;
    taud = next;
  }

  // --- epilogue: p/val in f32, regions via f64 compares, NT stores ---
  float* out_p = out;
  float* out_r = out + (size_t)B * (size_t)K;
  float* out_t = out + 2ull * (size_t)B * (size_t)K;
  float* out_v = out_t + B;

  const float tf = (float)taud;
  float vloc = 0.f;
  #pragma unroll
  for (int j = 0; j < 4; ++j) {
    vfloat4 p4v, r4v;
    #pragma unroll
    for (int q = 0; q < 4; ++q) {
      int t = j * 4 + q;
      float pf = fminf(fmaxf(zf[t] - tf, 0.f), uf[t]);   // v_med3_f32
      float d = pf - zf[t];
      vloc = fmaf(d, d, vloc);
      double xd = (double)zf[t] - taud;                  // numpy-exact bounds
      float rg = (xd <= 0.0) ? 0.f : ((xd >= (double)uf[t]) ? 2.f : 1.f);
      p4v[q] = pf;
      r4v[q] = rg;
    }
    __builtin_nontemporal_store(p4v, &((vfloat4*)(out_p + base))[j * 64 + lane]);
    __builtin_nontemporal_store(r4v, &((vfloat4*)(out_r + base))[j * 64 + lane]);
  }

  float vtot = wave_sum(vloc);
  if (lane == 0) {
    out_t[row] = tf;
    out_v[row] = 0.5f * vtot;
  }
}

extern "C" void kernel_launch(void* const* d_in, const int* in_sizes, int n_in,
                              void* d_out, int out_size, void* d_ws, size_t ws_size,
                              hipStream_t stream) {
  const float* z = (const float*)d_in[0];
  const float* u = (const float*)d_in[1];
  float* out = (float*)d_out;
  const int K = 1024;
  const int B = in_sizes[0] / K;
  csparsemax_kernel<<<B, 64, 0, stream>>>(z, u, out, B);
}